// Round 1
// baseline (101.185 us; speedup 1.0000x reference)
//
#include <hip/hip_runtime.h>
#include <math.h>

#define CCH 64
#define HW 441
#define HWP 448
#define NB2 25
#define PANEL (HWP * CCH)   // 28672 halves per image panel
#define TSTR 2048           // halves per 32-row tile (32 rows x 64 ch)
#define NJT 14              // j-tiles of 32 (448/32)

typedef _Float16 half8 __attribute__((ext_vector_type(8)));
typedef __fp16 h2 __attribute__((ext_vector_type(2)));
typedef float f32x16 __attribute__((ext_vector_type(16)));

// ---- kernel 1: fold mask + 1/norm into f16 descriptors, write in 32x32 MFMA
// operand fragment order: for tile of 32 rows, lane l holds row (l&31),
// k = (l>>5)*8 + e within each kfrag f (k_global = f*16 + ...).
// Address: panel + tile*2048 + f*512 + (l>>5)*256*... == tile*2048 + f*512 + l*8.
// Row i therefore stores halves [f*16+h*8+e] at tile*2048 + f*512 + h*256 + (i&31)*8.
// Also zeroes d_out.
__global__ __launch_bounds__(64) void normalize_frag_kernel(
        const float* __restrict__ x1, const float* __restrict__ m1,
        const float* __restrict__ x2, const float* __restrict__ m2,
        _Float16* __restrict__ qh, _Float16* __restrict__ sh,
        float* __restrict__ out, int nout, int n1rows, int nrows) {
    int idx = blockIdx.x * blockDim.x + threadIdx.x;
    if (idx < nout) out[idx] = 0.f;
    if (idx >= nrows) return;
    const float* x; const float* mk; _Float16* outp; int rb;
    if (idx < n1rows) { x = x1; mk = m1; outp = qh; rb = idx; }
    else             { x = x2; mk = m2; outp = sh; rb = idx - n1rows; }
    int b = rb / HWP, i = rb - b * HWP;
    float vals[CCH];
    if (i < HW) {
        const float* xb = x + (size_t)b * CCH * HW + i;
        float ss = 0.f;
#pragma unroll
        for (int c = 0; c < CCH; ++c) { float v = xb[c * HW]; vals[c] = v; ss += v * v; }
        float scale = mk[b * HW + i] * rsqrtf(ss);
#pragma unroll
        for (int c = 0; c < CCH; ++c) vals[c] *= scale;
    } else {
#pragma unroll
        for (int c = 0; c < CCH; ++c) vals[c] = 0.f;
    }
    _Float16* pb = outp + (size_t)b * PANEL + (size_t)(i >> 5) * TSTR + (i & 31) * 8;
#pragma unroll
    for (int f = 0; f < 4; ++f) {
#pragma unroll
        for (int hh = 0; hh < 2; ++hh) {
            half8 h;
#pragma unroll
            for (int e = 0; e < 8; ++e) h[e] = (_Float16)vals[f * 16 + hh * 8 + e];
            *(half8*)(pb + f * 512 + hh * 256) = h;
        }
    }
}

static __device__ __forceinline__ h2 hmax2(h2 a, h2 b) {
    return __builtin_elementwise_max(a, b);
}
static __device__ __forceinline__ h2 hmin2(h2 a, h2 b) {
    return __builtin_elementwise_min(a, b);
}

// packed top-3 insert: lo/hi halves are two independent triples. 5 packed ops.
#define PK_INSERT(v, p0, p1, p2)           \
    do {                                   \
        h2 _m = hmax2(p0, v);              \
        h2 _c = hmin2(p0, v);              \
        p0 = _m;                           \
        _m = hmax2(p1, _c);                \
        _c = hmin2(p1, _c);                \
        p1 = _m;                           \
        p2 = hmax2(p2, _c);                \
    } while (0)

// merge two desc-sorted f32 triples -> top3 of union in (t0,t1,t2)
#define MERGE3(t0, t1, t2, b0, b1, b2)            \
    do {                                          \
        float _m0 = fmaxf(t0, b0);                \
        float _n0 = fminf(t0, b0);                \
        float _m1 = fmaxf(t1, b1);                \
        float _t2 = fmaxf(t2, b2);                \
        t0 = _m0;                                 \
        t1 = fmaxf(_n0, _m1);                     \
        t2 = fmaxf(fminf(_n0, _m1), _t2);         \
    } while (0)

#define MFMA32(z, c, q) z = __builtin_amdgcn_mfma_f32_32x32x16_f16(c, q, z, 0, 0, 0)

// ---- kernel 2: 7 blocks per (a,b) pair. Block = 2 waves; wave w owns
// i-tile (g*2 + w) (32 query rows) and sweeps ALL 14 j-tiles of 32.
// Both waves stream identical s addresses -> L1 dedup on the shared CU.
// D-layout of 32x32x16: col = lane&31 = i, row = (reg&3)+8*(reg>>2)+4*(lane>>5) = j.
// Each lane maintains top-3 (packed lo/hi j-streams) for ONE i-column.
// No LDS, no __syncthreads; one atomicAdd per wave.
__global__ __launch_bounds__(128, 5) void sim_topk_mfma(const _Float16* __restrict__ qh,
                                                        const _Float16* __restrict__ sh,
                                                        float* __restrict__ out) {
    int blk = blockIdx.x;
    int pair = blk / 7, g = blk - pair * 7;
    int a = pair / NB2, b = pair - a * NB2;
    int tid = threadIdx.x, wave = tid >> 6, lane = tid & 63;
    int hi = lane >> 5;
    const float NEG = -1e30f;
    const h2 NEGH = {(__fp16)-65504.f, (__fp16)-65504.f};

    const _Float16* qt = qh + (size_t)a * PANEL + (size_t)(g * 2 + wave) * TSTR + lane * 8;
    half8 qf0 = *(const half8*)(qt);
    half8 qf1 = *(const half8*)(qt + 512);
    half8 qf2 = *(const half8*)(qt + 1024);
    half8 qf3 = *(const half8*)(qt + 1536);

    const _Float16* sp = sh + (size_t)b * PANEL + lane * 8;
    half8 c0 = *(const half8*)(sp);
    half8 c1 = *(const half8*)(sp + 512);
    half8 c2 = *(const half8*)(sp + 1024);
    half8 c3 = *(const half8*)(sp + 1536);

    h2 p0 = NEGH, p1 = NEGH, p2 = NEGH;

    for (int jt = 0; jt < NJT - 1; ++jt) {
        // prefetch next s-tile (tile jt+1; last iter fetches tile 13 for epilogue)
        const _Float16* np = sp + (size_t)(jt + 1) * TSTR;
        half8 n0 = *(const half8*)(np);
        half8 n1 = *(const half8*)(np + 512);
        half8 n2 = *(const half8*)(np + 1024);
        half8 n3 = *(const half8*)(np + 1536);

        f32x16 z = {0.f, 0.f, 0.f, 0.f, 0.f, 0.f, 0.f, 0.f,
                    0.f, 0.f, 0.f, 0.f, 0.f, 0.f, 0.f, 0.f};
        MFMA32(z, c0, qf0);
        MFMA32(z, c1, qf1);
        MFMA32(z, c2, qf2);
        MFMA32(z, c3, qf3);
#pragma unroll
        for (int r = 0; r < 8; ++r) {
            h2 c = __builtin_amdgcn_cvt_pkrtz(z[2 * r], z[2 * r + 1]);
            PK_INSERT(c, p0, p1, p2);
        }
        c0 = n0; c1 = n1; c2 = n2; c3 = n3;
    }

    // masked tile 13: j = 416 + row, valid iff row < 25 (441-416).
    // row = (reg&3) + 8*(reg>>2) + 4*hi -> regs 0..11 always valid,
    // reg 12 valid iff hi==0, regs 13..15 never valid (dropped).
    {
        f32x16 z = {0.f, 0.f, 0.f, 0.f, 0.f, 0.f, 0.f, 0.f,
                    0.f, 0.f, 0.f, 0.f, 0.f, 0.f, 0.f, 0.f};
        MFMA32(z, c0, qf0);
        MFMA32(z, c1, qf1);
        MFMA32(z, c2, qf2);
        MFMA32(z, c3, qf3);
#pragma unroll
        for (int r = 0; r < 6; ++r) {
            h2 c = __builtin_amdgcn_cvt_pkrtz(z[2 * r], z[2 * r + 1]);
            PK_INSERT(c, p0, p1, p2);
        }
        float z12 = hi ? NEG : z[12];
        h2 c = __builtin_amdgcn_cvt_pkrtz(z12, NEG);  // NEG saturates to -65504 under RTZ
        PK_INSERT(c, p0, p1, p2);
    }

    // merge lo/hi packed j-streams in f32
    float a0 = (float)p0[0], a1 = (float)p1[0], a2 = (float)p2[0];
    float b0 = (float)p0[1], b1 = (float)p1[1], b2 = (float)p2[1];
    MERGE3(a0, a1, a2, b0, b1, b2);
    // cross-lane merge: column i lives in lane and lane^32 (different j-subsets)
    b0 = __shfl_xor(a0, 32); b1 = __shfl_xor(a1, 32); b2 = __shfl_xor(a2, 32);
    MERGE3(a0, a1, a2, b0, b1, b2);
    // after merge both lanes hold identical triples; count each column once
    float rsum = hi ? 0.f : (a0 + a1 + a2);
#pragma unroll
    for (int off = 32; off > 0; off >>= 1) rsum += __shfl_xor(rsum, off);
    if (lane == 0) atomicAdd(&out[pair], rsum);
}

extern "C" void kernel_launch(void* const* d_in, const int* in_sizes, int n_in,
                              void* d_out, int out_size, void* d_ws, size_t ws_size,
                              hipStream_t stream) {
    const float* x1 = (const float*)d_in[0];
    const float* x2 = (const float*)d_in[1];
    const float* m1 = (const float*)d_in[2];
    const float* m2 = (const float*)d_in[3];
    float* out = (float*)d_out;

    int B1 = in_sizes[0] / (CCH * HW);
    int B2 = in_sizes[1] / (CCH * HW);

    _Float16* qh = (_Float16*)d_ws;
    _Float16* sh = qh + (size_t)B1 * PANEL;

    int n1 = B1 * HWP, ntot = (B1 + B2) * HWP;
    normalize_frag_kernel<<<(ntot + 63) / 64, 64, 0, stream>>>(
        x1, m1, x2, m2, qh, sh, out, B1 * B2, n1, ntot);
    sim_topk_mfma<<<B1 * B2 * 7, 128, 0, stream>>>(qh, sh, out);
}

// Round 2
// 97.426 us; speedup vs baseline: 1.0386x; 1.0386x over previous
//
#include <hip/hip_runtime.h>
#include <math.h>

#define CCH 64
#define HW 441
#define HWP 448
#define NB2 25
#define PANEL (HWP * CCH)   // 28672 halves per image panel
#define TSTR 2048           // halves per 32-row tile (32 rows x 64 ch)
#define NJT 14              // j-tiles of 32 (448/32)

typedef _Float16 half8 __attribute__((ext_vector_type(8)));
typedef __fp16 h2 __attribute__((ext_vector_type(2)));
typedef float f32x16 __attribute__((ext_vector_type(16)));

// ---- kernel 1: fold mask + 1/norm into f16 descriptors, write in 32x32 MFMA
// operand fragment order: for tile of 32 rows, lane l holds row (l&31),
// halves [f*16 + h*8 + e] of row i live at tile*2048 + f*512 + h*256 + (i&31)*8.
// Also zeroes d_out.
__global__ __launch_bounds__(64) void normalize_frag_kernel(
        const float* __restrict__ x1, const float* __restrict__ m1,
        const float* __restrict__ x2, const float* __restrict__ m2,
        _Float16* __restrict__ qh, _Float16* __restrict__ sh,
        float* __restrict__ out, int nout, int n1rows, int nrows) {
    int idx = blockIdx.x * blockDim.x + threadIdx.x;
    if (idx < nout) out[idx] = 0.f;
    if (idx >= nrows) return;
    const float* x; const float* mk; _Float16* outp; int rb;
    if (idx < n1rows) { x = x1; mk = m1; outp = qh; rb = idx; }
    else             { x = x2; mk = m2; outp = sh; rb = idx - n1rows; }
    int b = rb / HWP, i = rb - b * HWP;
    float vals[CCH];
    if (i < HW) {
        const float* xb = x + (size_t)b * CCH * HW + i;
        float ss = 0.f;
#pragma unroll
        for (int c = 0; c < CCH; ++c) { float v = xb[c * HW]; vals[c] = v; ss += v * v; }
        float scale = mk[b * HW + i] * rsqrtf(ss);
#pragma unroll
        for (int c = 0; c < CCH; ++c) vals[c] *= scale;
    } else {
#pragma unroll
        for (int c = 0; c < CCH; ++c) vals[c] = 0.f;
    }
    _Float16* pb = outp + (size_t)b * PANEL + (size_t)(i >> 5) * TSTR + (i & 31) * 8;
#pragma unroll
    for (int f = 0; f < 4; ++f) {
#pragma unroll
        for (int hh = 0; hh < 2; ++hh) {
            half8 h;
#pragma unroll
            for (int e = 0; e < 8; ++e) h[e] = (_Float16)vals[f * 16 + hh * 8 + e];
            *(half8*)(pb + f * 512 + hh * 256) = h;
        }
    }
}

static __device__ __forceinline__ h2 hmax2(h2 a, h2 b) {
    return __builtin_elementwise_max(a, b);
}
static __device__ __forceinline__ h2 hmin2(h2 a, h2 b) {
    return __builtin_elementwise_min(a, b);
}

// packed top-3 insert: lo/hi halves are two independent triples. 5 packed ops.
#define PK_INSERT(v, p0, p1, p2)           \
    do {                                   \
        h2 _m = hmax2(p0, v);              \
        h2 _c = hmin2(p0, v);              \
        p0 = _m;                           \
        _m = hmax2(p1, _c);                \
        _c = hmin2(p1, _c);                \
        p1 = _m;                           \
        p2 = hmax2(p2, _c);                \
    } while (0)

// merge two desc-sorted f32 triples -> top3 of union in (t0,t1,t2)
#define MERGE3(t0, t1, t2, b0, b1, b2)            \
    do {                                          \
        float _m0 = fmaxf(t0, b0);                \
        float _n0 = fminf(t0, b0);                \
        float _m1 = fmaxf(t1, b1);                \
        float _t2 = fmaxf(t2, b2);                \
        t0 = _m0;                                 \
        t1 = fmaxf(_n0, _m1);                     \
        t2 = fmaxf(fminf(_n0, _m1), _t2);         \
    } while (0)

#define MFMA32(z, c, q) z = __builtin_amdgcn_mfma_f32_32x32x16_f16(c, q, z, 0, 0, 0)

// ---- kernel 2: one wave per block, 7 blocks per (a,b) pair. Wave owns TWO
// i-tiles {2g, 2g+1} (64 query rows) and sweeps all 14 j-tiles of 32 once.
// Sharing the s-stream across 2 i-tiles halves L2 traffic per MFMA and gives
// two independent MFMA accumulator chains (in-wave matrix-pipe ILP).
// D-layout of 32x32x16: col = lane&31 = i, row = (reg&3)+8*(reg>>2)+4*(lane>>5) = j.
// No LDS, no __syncthreads; one atomicAdd per wave.
__global__ __launch_bounds__(64, 4) void sim_topk_mfma(const _Float16* __restrict__ qh,
                                                       const _Float16* __restrict__ sh,
                                                       float* __restrict__ out) {
    int blk = blockIdx.x;
    int pair = blk / 7, g = blk - pair * 7;
    int a = pair / NB2, b = pair - a * NB2;
    int lane = threadIdx.x;   // 64-thread block = 1 wave
    int hi = lane >> 5;
    const float NEG = -1e30f;
    const h2 NEGH = {(__fp16)-65504.f, (__fp16)-65504.f};
    const f32x16 FZ = {0.f, 0.f, 0.f, 0.f, 0.f, 0.f, 0.f, 0.f,
                       0.f, 0.f, 0.f, 0.f, 0.f, 0.f, 0.f, 0.f};

    const _Float16* qt = qh + (size_t)a * PANEL + (size_t)(g * 2) * TSTR + lane * 8;
    half8 qa0 = *(const half8*)(qt);
    half8 qa1 = *(const half8*)(qt + 512);
    half8 qa2 = *(const half8*)(qt + 1024);
    half8 qa3 = *(const half8*)(qt + 1536);
    half8 qb0 = *(const half8*)(qt + 2048);
    half8 qb1 = *(const half8*)(qt + 2560);
    half8 qb2 = *(const half8*)(qt + 3072);
    half8 qb3 = *(const half8*)(qt + 3584);

    const _Float16* sp = sh + (size_t)b * PANEL + lane * 8;
    half8 c0 = *(const half8*)(sp);
    half8 c1 = *(const half8*)(sp + 512);
    half8 c2 = *(const half8*)(sp + 1024);
    half8 c3 = *(const half8*)(sp + 1536);

    h2 pa0 = NEGH, pa1 = NEGH, pa2 = NEGH;   // i-tile 2g
    h2 pb0 = NEGH, pb1 = NEGH, pb2 = NEGH;   // i-tile 2g+1

    for (int jt = 0; jt < NJT - 1; ++jt) {
        // prefetch next s-tile (last iter fetches tile 13 for the masked epilogue)
        const _Float16* np = sp + (size_t)(jt + 1) * TSTR;
        half8 n0 = *(const half8*)(np);
        half8 n1 = *(const half8*)(np + 512);
        half8 n2 = *(const half8*)(np + 1024);
        half8 n3 = *(const half8*)(np + 1536);

        __builtin_amdgcn_s_setprio(1);
        f32x16 z0 = FZ, z1 = FZ;
        MFMA32(z0, c0, qa0); MFMA32(z1, c0, qb0);
        MFMA32(z0, c1, qa1); MFMA32(z1, c1, qb1);
        MFMA32(z0, c2, qa2); MFMA32(z1, c2, qb2);
        MFMA32(z0, c3, qa3); MFMA32(z1, c3, qb3);
        __builtin_amdgcn_s_setprio(0);
#pragma unroll
        for (int r = 0; r < 8; ++r) {
            h2 ca = __builtin_amdgcn_cvt_pkrtz(z0[2 * r], z0[2 * r + 1]);
            h2 cb = __builtin_amdgcn_cvt_pkrtz(z1[2 * r], z1[2 * r + 1]);
            PK_INSERT(ca, pa0, pa1, pa2);
            PK_INSERT(cb, pb0, pb1, pb2);
        }
        c0 = n0; c1 = n1; c2 = n2; c3 = n3;
    }

    // masked tile 13: j = 416 + row, valid iff row < 25 (441-416).
    // row = (reg&3) + 8*(reg>>2) + 4*hi -> regs 0..11 always valid,
    // reg 12 valid iff hi==0, regs 13..15 never valid (dropped).
    {
        __builtin_amdgcn_s_setprio(1);
        f32x16 z0 = FZ, z1 = FZ;
        MFMA32(z0, c0, qa0); MFMA32(z1, c0, qb0);
        MFMA32(z0, c1, qa1); MFMA32(z1, c1, qb1);
        MFMA32(z0, c2, qa2); MFMA32(z1, c2, qb2);
        MFMA32(z0, c3, qa3); MFMA32(z1, c3, qb3);
        __builtin_amdgcn_s_setprio(0);
#pragma unroll
        for (int r = 0; r < 6; ++r) {
            h2 ca = __builtin_amdgcn_cvt_pkrtz(z0[2 * r], z0[2 * r + 1]);
            h2 cb = __builtin_amdgcn_cvt_pkrtz(z1[2 * r], z1[2 * r + 1]);
            PK_INSERT(ca, pa0, pa1, pa2);
            PK_INSERT(cb, pb0, pb1, pb2);
        }
        float za = hi ? NEG : z0[12];
        float zb = hi ? NEG : z1[12];
        h2 ca = __builtin_amdgcn_cvt_pkrtz(za, NEG);  // NEG saturates to -65504 (RTZ)
        h2 cb = __builtin_amdgcn_cvt_pkrtz(zb, NEG);
        PK_INSERT(ca, pa0, pa1, pa2);
        PK_INSERT(cb, pb0, pb1, pb2);
    }

    // merge lo/hi packed j-streams in f32, then cross-lane (lane ^ 32) merge:
    // column i of each tile lives in lane and lane^32 with disjoint j-subsets.
    float a0 = (float)pa0[0], a1 = (float)pa1[0], a2 = (float)pa2[0];
    float b0 = (float)pa0[1], b1 = (float)pa1[1], b2 = (float)pa2[1];
    MERGE3(a0, a1, a2, b0, b1, b2);
    b0 = __shfl_xor(a0, 32); b1 = __shfl_xor(a1, 32); b2 = __shfl_xor(a2, 32);
    MERGE3(a0, a1, a2, b0, b1, b2);
    float suma = a0 + a1 + a2;

    a0 = (float)pb0[0]; a1 = (float)pb1[0]; a2 = (float)pb2[0];
    b0 = (float)pb0[1]; b1 = (float)pb1[1]; b2 = (float)pb2[1];
    MERGE3(a0, a1, a2, b0, b1, b2);
    b0 = __shfl_xor(a0, 32); b1 = __shfl_xor(a1, 32); b2 = __shfl_xor(a2, 32);
    MERGE3(a0, a1, a2, b0, b1, b2);
    float sumb = a0 + a1 + a2;

    // after the xor-32 merge both lanes hold identical triples; count each column once
    float rsum = hi ? 0.f : (suma + sumb);
#pragma unroll
    for (int off = 32; off > 0; off >>= 1) rsum += __shfl_xor(rsum, off);
    if (lane == 0) atomicAdd(&out[pair], rsum);
}

extern "C" void kernel_launch(void* const* d_in, const int* in_sizes, int n_in,
                              void* d_out, int out_size, void* d_ws, size_t ws_size,
                              hipStream_t stream) {
    const float* x1 = (const float*)d_in[0];
    const float* x2 = (const float*)d_in[1];
    const float* m1 = (const float*)d_in[2];
    const float* m2 = (const float*)d_in[3];
    float* out = (float*)d_out;

    int B1 = in_sizes[0] / (CCH * HW);
    int B2 = in_sizes[1] / (CCH * HW);

    _Float16* qh = (_Float16*)d_ws;
    _Float16* sh = qh + (size_t)B1 * PANEL;

    int n1 = B1 * HWP, ntot = (B1 + B2) * HWP;
    normalize_frag_kernel<<<(ntot + 63) / 64, 64, 0, stream>>>(
        x1, m1, x2, m2, qh, sh, out, B1 * B2, n1, ntot);
    sim_topk_mfma<<<B1 * B2 * 7, 64, 0, stream>>>(qh, sh, out);
}

// Round 3
// 96.987 us; speedup vs baseline: 1.0433x; 1.0045x over previous
//
#include <hip/hip_runtime.h>
#include <math.h>

#define CCH 64
#define HW 441
#define HWP 448
#define NB2 25
#define PANEL (HWP * CCH)   // 28672 halves per image panel
#define TSTR 2048           // halves per 32-row tile (32 rows x 64 ch)
#define NJT 14              // j-tiles of 32 (448/32)

typedef _Float16 half8 __attribute__((ext_vector_type(8)));
typedef __fp16 h2 __attribute__((ext_vector_type(2)));
typedef float f32x16 __attribute__((ext_vector_type(16)));

// ---- kernel 1: fold mask + 1/norm into f16 descriptors, write in 32x32 MFMA
// operand fragment order: for tile of 32 rows, lane l holds row (l&31),
// halves [f*16 + h*8 + e] of row i live at tile*2048 + f*512 + h*256 + (i&31)*8.
// Also zeroes d_out.
__global__ __launch_bounds__(64) void normalize_frag_kernel(
        const float* __restrict__ x1, const float* __restrict__ m1,
        const float* __restrict__ x2, const float* __restrict__ m2,
        _Float16* __restrict__ qh, _Float16* __restrict__ sh,
        float* __restrict__ out, int nout, int n1rows, int nrows) {
    int idx = blockIdx.x * blockDim.x + threadIdx.x;
    if (idx < nout) out[idx] = 0.f;
    if (idx >= nrows) return;
    const float* x; const float* mk; _Float16* outp; int rb;
    if (idx < n1rows) { x = x1; mk = m1; outp = qh; rb = idx; }
    else             { x = x2; mk = m2; outp = sh; rb = idx - n1rows; }
    int b = rb / HWP, i = rb - b * HWP;
    float vals[CCH];
    if (i < HW) {
        const float* xb = x + (size_t)b * CCH * HW + i;
        float ss = 0.f;
#pragma unroll
        for (int c = 0; c < CCH; ++c) { float v = xb[c * HW]; vals[c] = v; ss += v * v; }
        float scale = mk[b * HW + i] * rsqrtf(ss);
#pragma unroll
        for (int c = 0; c < CCH; ++c) vals[c] *= scale;
    } else {
#pragma unroll
        for (int c = 0; c < CCH; ++c) vals[c] = 0.f;
    }
    _Float16* pb = outp + (size_t)b * PANEL + (size_t)(i >> 5) * TSTR + (i & 31) * 8;
#pragma unroll
    for (int f = 0; f < 4; ++f) {
#pragma unroll
        for (int hh = 0; hh < 2; ++hh) {
            half8 h;
#pragma unroll
            for (int e = 0; e < 8; ++e) h[e] = (_Float16)vals[f * 16 + hh * 8 + e];
            *(half8*)(pb + f * 512 + hh * 256) = h;
        }
    }
}

static __device__ __forceinline__ h2 hmax2(h2 a, h2 b) {
    return __builtin_elementwise_max(a, b);
}
static __device__ __forceinline__ h2 hmin2(h2 a, h2 b) {
    return __builtin_elementwise_min(a, b);
}

// packed top-3 insert: lo/hi halves are two independent triples. 5 packed ops.
#define PK_INSERT(v, p0, p1, p2)           \
    do {                                   \
        h2 _m = hmax2(p0, v);              \
        h2 _c = hmin2(p0, v);              \
        p0 = _m;                           \
        _m = hmax2(p1, _c);                \
        _c = hmin2(p1, _c);                \
        p1 = _m;                           \
        p2 = hmax2(p2, _c);                \
    } while (0)

// merge two desc-sorted f32 triples -> top3 of union in (t0,t1,t2)
#define MERGE3(t0, t1, t2, b0, b1, b2)            \
    do {                                          \
        float _m0 = fmaxf(t0, b0);                \
        float _n0 = fminf(t0, b0);                \
        float _m1 = fmaxf(t1, b1);                \
        float _t2 = fmaxf(t2, b2);                \
        t0 = _m0;                                 \
        t1 = fmaxf(_n0, _m1);                     \
        t2 = fmaxf(fminf(_n0, _m1), _t2);         \
    } while (0)

#define MFMA32(z, c, q) z = __builtin_amdgcn_mfma_f32_32x32x16_f16(c, q, z, 0, 0, 0)

// Two i-tiles against the current s-tile (c0..c3), full 16-reg insert.
#define DO_PAIR(ta, tb)                                                     \
    do {                                                                    \
        f32x16 z0 = FZ, z1 = FZ;                                            \
        MFMA32(z0, c0, qf##ta##0); MFMA32(z1, c0, qf##tb##0);               \
        MFMA32(z0, c1, qf##ta##1); MFMA32(z1, c1, qf##tb##1);               \
        MFMA32(z0, c2, qf##ta##2); MFMA32(z1, c2, qf##tb##2);               \
        MFMA32(z0, c3, qf##ta##3); MFMA32(z1, c3, qf##tb##3);               \
        _Pragma("unroll")                                                   \
        for (int r = 0; r < 8; ++r) {                                       \
            h2 ca = __builtin_amdgcn_cvt_pkrtz(z0[2 * r], z0[2 * r + 1]);   \
            h2 cb = __builtin_amdgcn_cvt_pkrtz(z1[2 * r], z1[2 * r + 1]);   \
            PK_INSERT(ca, p0[ta], p1[ta], p2[ta]);                          \
            PK_INSERT(cb, p0[tb], p1[tb], p2[tb]);                          \
        }                                                                   \
    } while (0)

#define DO_SINGLE(ta)                                                       \
    do {                                                                    \
        f32x16 z0 = FZ;                                                     \
        MFMA32(z0, c0, qf##ta##0);                                          \
        MFMA32(z0, c1, qf##ta##1);                                          \
        MFMA32(z0, c2, qf##ta##2);                                          \
        MFMA32(z0, c3, qf##ta##3);                                          \
        _Pragma("unroll")                                                   \
        for (int r = 0; r < 8; ++r) {                                       \
            h2 ca = __builtin_amdgcn_cvt_pkrtz(z0[2 * r], z0[2 * r + 1]);   \
            PK_INSERT(ca, p0[ta], p1[ta], p2[ta]);                          \
        }                                                                   \
    } while (0)

// Masked tile 13: j = 416 + row, valid iff row < 25 (441-416).
// row = (reg&3) + 8*(reg>>2) + 4*hi -> regs 0..11 always valid,
// reg 12 valid iff hi==0, regs 13..15 never valid (dropped).
#define DO_PAIR_M(ta, tb)                                                   \
    do {                                                                    \
        f32x16 z0 = FZ, z1 = FZ;                                            \
        MFMA32(z0, c0, qf##ta##0); MFMA32(z1, c0, qf##tb##0);               \
        MFMA32(z0, c1, qf##ta##1); MFMA32(z1, c1, qf##tb##1);               \
        MFMA32(z0, c2, qf##ta##2); MFMA32(z1, c2, qf##tb##2);               \
        MFMA32(z0, c3, qf##ta##3); MFMA32(z1, c3, qf##tb##3);               \
        _Pragma("unroll")                                                   \
        for (int r = 0; r < 6; ++r) {                                       \
            h2 ca = __builtin_amdgcn_cvt_pkrtz(z0[2 * r], z0[2 * r + 1]);   \
            h2 cb = __builtin_amdgcn_cvt_pkrtz(z1[2 * r], z1[2 * r + 1]);   \
            PK_INSERT(ca, p0[ta], p1[ta], p2[ta]);                          \
            PK_INSERT(cb, p0[tb], p1[tb], p2[tb]);                          \
        }                                                                   \
        float za = hi ? NEG : z0[12];                                       \
        float zb = hi ? NEG : z1[12];                                       \
        h2 ca = __builtin_amdgcn_cvt_pkrtz(za, NEG);                        \
        h2 cb = __builtin_amdgcn_cvt_pkrtz(zb, NEG);                        \
        PK_INSERT(ca, p0[ta], p1[ta], p2[ta]);                              \
        PK_INSERT(cb, p0[tb], p1[tb], p2[tb]);                              \
    } while (0)

#define DO_SINGLE_M(ta)                                                     \
    do {                                                                    \
        f32x16 z0 = FZ;                                                     \
        MFMA32(z0, c0, qf##ta##0);                                          \
        MFMA32(z0, c1, qf##ta##1);                                          \
        MFMA32(z0, c2, qf##ta##2);                                          \
        MFMA32(z0, c3, qf##ta##3);                                          \
        _Pragma("unroll")                                                   \
        for (int r = 0; r < 6; ++r) {                                       \
            h2 ca = __builtin_amdgcn_cvt_pkrtz(z0[2 * r], z0[2 * r + 1]);   \
            PK_INSERT(ca, p0[ta], p1[ta], p2[ta]);                          \
        }                                                                   \
        float za = hi ? NEG : z0[12];                                       \
        h2 ca = __builtin_amdgcn_cvt_pkrtz(za, NEG);                        \
        PK_INSERT(ca, p0[ta], p1[ta], p2[ta]);                              \
    } while (0)

#define LOAD_Q(t)                                                           \
    half8 qf##t##0 = *(const half8*)(qt + (t) * 2048);                      \
    half8 qf##t##1 = *(const half8*)(qt + (t) * 2048 + 512);                \
    half8 qf##t##2 = *(const half8*)(qt + (t) * 2048 + 1024);               \
    half8 qf##t##3 = *(const half8*)(qt + (t) * 2048 + 1536);

// ---- kernel 2: one wave per block, 2 blocks per (a,b) pair. Wave owns SEVEN
// i-tiles (g*7 .. g*7+6; 224 query rows, 112 VGPR of q frags) and sweeps the
// s-panel ONCE. Per-pair L2 traffic: 2 x (57KB s + 28KB q) = 170KB (was 458KB)
// -> MFMA-bound. Two rotating accumulator chains for matrix-pipe ILP.
// D-layout of 32x32x16: col = lane&31 = i, row = (reg&3)+8*(reg>>2)+4*(lane>>5) = j.
// No LDS, no __syncthreads; one atomicAdd per wave.
__global__ __launch_bounds__(64, 2) void sim_topk_mfma(const _Float16* __restrict__ qh,
                                                       const _Float16* __restrict__ sh,
                                                       float* __restrict__ out) {
    int blk = blockIdx.x;
    int pair = blk >> 1, g = blk & 1;
    int a = pair / NB2, b = pair - a * NB2;
    int lane = threadIdx.x;   // 64-thread block = 1 wave
    int hi = lane >> 5;
    const float NEG = -1e30f;
    const h2 NEGH = {(__fp16)-65504.f, (__fp16)-65504.f};
    const f32x16 FZ = {0.f, 0.f, 0.f, 0.f, 0.f, 0.f, 0.f, 0.f,
                       0.f, 0.f, 0.f, 0.f, 0.f, 0.f, 0.f, 0.f};

    const _Float16* qt = qh + (size_t)a * PANEL + (size_t)(g * 7) * TSTR + lane * 8;
    LOAD_Q(0) LOAD_Q(1) LOAD_Q(2) LOAD_Q(3) LOAD_Q(4) LOAD_Q(5) LOAD_Q(6)

    const _Float16* sp = sh + (size_t)b * PANEL + lane * 8;
    half8 c0 = *(const half8*)(sp);
    half8 c1 = *(const half8*)(sp + 512);
    half8 c2 = *(const half8*)(sp + 1024);
    half8 c3 = *(const half8*)(sp + 1536);

    h2 p0[7], p1[7], p2[7];
#pragma unroll
    for (int t = 0; t < 7; ++t) { p0[t] = NEGH; p1[t] = NEGH; p2[t] = NEGH; }

    for (int jt = 0; jt < NJT - 1; ++jt) {
        // prefetch next s-tile (last iter fetches tile 13 for the masked epilogue)
        const _Float16* np = sp + (size_t)(jt + 1) * TSTR;
        half8 n0 = *(const half8*)(np);
        half8 n1 = *(const half8*)(np + 512);
        half8 n2 = *(const half8*)(np + 1024);
        half8 n3 = *(const half8*)(np + 1536);

        __builtin_amdgcn_s_setprio(1);
        DO_PAIR(0, 1);
        DO_PAIR(2, 3);
        DO_PAIR(4, 5);
        DO_SINGLE(6);
        __builtin_amdgcn_s_setprio(0);
        c0 = n0; c1 = n1; c2 = n2; c3 = n3;
    }

    {   // masked final j-tile
        __builtin_amdgcn_s_setprio(1);
        DO_PAIR_M(0, 1);
        DO_PAIR_M(2, 3);
        DO_PAIR_M(4, 5);
        DO_SINGLE_M(6);
        __builtin_amdgcn_s_setprio(0);
    }

    // per-tile: merge lo/hi packed j-streams in f32, then cross-lane (lane^32)
    // merge (column i lives in lane and lane^32 with disjoint j-subsets).
    float rsum = 0.f;
#pragma unroll
    for (int t = 0; t < 7; ++t) {
        float a0 = (float)p0[t][0], a1 = (float)p1[t][0], a2 = (float)p2[t][0];
        float b0 = (float)p0[t][1], b1 = (float)p1[t][1], b2 = (float)p2[t][1];
        MERGE3(a0, a1, a2, b0, b1, b2);
        b0 = __shfl_xor(a0, 32); b1 = __shfl_xor(a1, 32); b2 = __shfl_xor(a2, 32);
        MERGE3(a0, a1, a2, b0, b1, b2);
        rsum += a0 + a1 + a2;
    }
    // after the xor-32 merges both half-waves hold identical triples; count once
    rsum = hi ? 0.f : rsum;
#pragma unroll
    for (int off = 32; off > 0; off >>= 1) rsum += __shfl_xor(rsum, off);
    if (lane == 0) atomicAdd(&out[pair], rsum);
}

extern "C" void kernel_launch(void* const* d_in, const int* in_sizes, int n_in,
                              void* d_out, int out_size, void* d_ws, size_t ws_size,
                              hipStream_t stream) {
    const float* x1 = (const float*)d_in[0];
    const float* x2 = (const float*)d_in[1];
    const float* m1 = (const float*)d_in[2];
    const float* m2 = (const float*)d_in[3];
    float* out = (float*)d_out;

    int B1 = in_sizes[0] / (CCH * HW);
    int B2 = in_sizes[1] / (CCH * HW);

    _Float16* qh = (_Float16*)d_ws;
    _Float16* sh = qh + (size_t)B1 * PANEL;

    int n1 = B1 * HWP, ntot = (B1 + B2) * HWP;
    normalize_frag_kernel<<<(ntot + 63) / 64, 64, 0, stream>>>(
        x1, m1, x2, m2, qh, sh, out, B1 * B2, n1, ntot);
    sim_topk_mfma<<<B1 * B2 * 2, 64, 0, stream>>>(qh, sh, out);
}